// Round 1
// baseline (357.166 us; speedup 1.0000x reference)
//
#include <hip/hip_runtime.h>
#include <math.h>

#define B 4096
#define C 5
#define NNEG 20
#define D 128
#define NROWS (C + C * NNEG)  // 105 rows per batch element (5 pos + 100 neg)
#define PER 4                 // batch elements per persistent block
#define NBLK (B / PER)        // 1024 blocks = 4 per CU, all co-resident

// stable log sigmoid: logsig(x) = min(x,0) - log1p(exp(-|x|))
__device__ __forceinline__ float log_sigmoid(float x) {
    return fminf(x, 0.0f) - log1pf(__expf(-fabsf(x)));
}

__device__ __forceinline__ int fetch_idx(const int* __restrict__ ow,
                                         const int* __restrict__ nw,
                                         int b, int r) {
    return (r < C) ? ow[b * C + r] : nw[b * (C * NNEG) + (r - C)];
}

// one row's dot + 8-lane butterfly + logsig (s is group-uniform after shuffles)
__device__ __forceinline__ float row_term(const float4 v1f[4], const float4 rwp[4],
                                          float sgn) {
    float s = 0.0f;
    #pragma unroll
    for (int k = 0; k < 4; ++k) {
        s += v1f[k].x * rwp[k].x + v1f[k].y * rwp[k].y
           + v1f[k].z * rwp[k].z + v1f[k].w * rwp[k].w;
    }
    s += __shfl_xor(s, 1, 64);
    s += __shfl_xor(s, 2, 64);
    s += __shfl_xor(s, 4, 64);
    return log_sigmoid(sgn * s);
}

// Persistent blocks: 1024 blocks x PER=4 batch elements. 256 threads = 4 waves
// = 32 row-groups of 8 lanes; group `base` owns row slots base+32p, p=0..3.
// Slots >= 105 are SKIPPED (group-uniform guard) instead of dummy-loaded.
// Cross-element software pipeline: next element's 4+1 index loads are issued
// while the current element's 16 float4 row gathers are still in flight, so
// the index round-trip latency is exposed once per block, not once per b.
__global__ __launch_bounds__(256, 4) void sgns_partial(
    const int* __restrict__ iword,
    const int* __restrict__ owords,
    const int* __restrict__ nwords,
    const float* __restrict__ emb1,
    const float* __restrict__ emb2,
    float* __restrict__ partial)
{
    const int tid  = threadIdx.x;
    const int lane = tid & 63;
    const int wave = tid >> 6;       // 0..3
    const int grp  = lane >> 3;      // 0..7
    const int j    = lane & 7;       // dim-slice owner within group
    const int base = wave * 8 + grp; // 0..31
    const bool valid3 = (base + 96) < NROWS;  // p=3 slot exists (base < 9)
    const float sgn0 = (base < C) ? 1.0f : -1.0f;  // p=0 slot sign

    __shared__ float wsum[2][4];     // double-buffered -> 1 barrier per element

    // ---- prologue: prefetch first element's indices ----
    const int b0 = blockIdx.x * PER;
    int centerN = iword[b0];
    int idxN[4];
    #pragma unroll
    for (int p = 0; p < 3; ++p)
        idxN[p] = fetch_idx(owords, nwords, b0, base + 32 * p);
    idxN[3] = valid3 ? fetch_idx(owords, nwords, b0, base + 96) : 0;

    for (int it = 0; it < PER; ++it) {
        const int b = b0 + it;
        const int centerC = centerN;
        int idxC[4];
        #pragma unroll
        for (int p = 0; p < 4; ++p) idxC[p] = idxN[p];

        // ---- issue v1 fragment + all row gathers for current element ----
        const float4* v1p = (const float4*)(emb1 + (long)centerC * D);
        float4 v1f[4];
        #pragma unroll
        for (int k = 0; k < 4; ++k) v1f[k] = v1p[j + 8 * k];

        float4 rw[4][4];
        #pragma unroll
        for (int p = 0; p < 3; ++p) {
            const float4* rp = (const float4*)(emb2 + (long)idxC[p] * D);
            #pragma unroll
            for (int k = 0; k < 4; ++k) rw[p][k] = rp[j + 8 * k];
        }
        if (valid3) {
            const float4* rp = (const float4*)(emb2 + (long)idxC[3] * D);
            #pragma unroll
            for (int k = 0; k < 4; ++k) rw[3][k] = rp[j + 8 * k];
        }

        // ---- prefetch next element's indices (hidden under row gathers) ----
        if (it + 1 < PER) {
            const int bn = b + 1;
            centerN = iword[bn];
            #pragma unroll
            for (int p = 0; p < 3; ++p)
                idxN[p] = fetch_idx(owords, nwords, bn, base + 32 * p);
            idxN[3] = valid3 ? fetch_idx(owords, nwords, bn, base + 96) : 0;
        }

        // ---- consume (bit-identical per-b arithmetic to prior kernel) ----
        float acc = 0.0f;
        acc += row_term(v1f, rw[0], sgn0);
        acc += row_term(v1f, rw[1], -1.0f);
        acc += row_term(v1f, rw[2], -1.0f);
        if (valid3)
            acc += row_term(v1f, rw[3], -1.0f);

        // acc is uniform within each 8-lane group -> reduce across groups only
        acc += __shfl_xor(acc, 8, 64);
        acc += __shfl_xor(acc, 16, 64);
        acc += __shfl_xor(acc, 32, 64);

        if (lane == 0) wsum[it & 1][wave] = acc;
        __syncthreads();
        if (tid == 0)
            partial[b] = wsum[it & 1][0] + wsum[it & 1][1]
                       + wsum[it & 1][2] + wsum[it & 1][3];
        // next iteration writes the other wsum buffer, so no second barrier
    }
}

// Single-block final reduction: out = -(sum of all logsig terms) / (B*C)
// (unchanged: keeps the summation tree, and thus the output bits, identical)
__global__ __launch_bounds__(256) void sgns_reduce(
    const float* __restrict__ partial,
    float* __restrict__ out)
{
    const int tid = threadIdx.x;
    float acc = 0.0f;
    for (int i = tid; i < B; i += 256) acc += partial[i];

    #pragma unroll
    for (int off = 32; off > 0; off >>= 1)
        acc += __shfl_xor(acc, off, 64);

    __shared__ float ws[4];
    if ((tid & 63) == 0) ws[tid >> 6] = acc;
    __syncthreads();
    if (tid == 0) out[0] = -(ws[0] + ws[1] + ws[2] + ws[3]) / (float)(B * C);
}

extern "C" void kernel_launch(void* const* d_in, const int* in_sizes, int n_in,
                              void* d_out, int out_size, void* d_ws, size_t ws_size,
                              hipStream_t stream) {
    const int*   iword  = (const int*)d_in[0];
    const int*   owords = (const int*)d_in[1];
    const int*   nwords = (const int*)d_in[2];
    const float* emb1   = (const float*)d_in[3];
    const float* emb2   = (const float*)d_in[4];
    float* out     = (float*)d_out;
    float* partial = (float*)d_ws;  // B floats = 16 KB

    sgns_partial<<<NBLK, 256, 0, stream>>>(iword, owords, nwords, emb1, emb2, partial);
    sgns_reduce<<<1, 256, 0, stream>>>(partial, out);
}